// Round 19
// baseline (96.861 us; speedup 1.0000x reference)
//
#include <hip/hip_runtime.h>
#include <hip/hip_bf16.h>
#include <math.h>

#define NF    50              // n_frequencies
#define DEMB  10              // embedding dim
#define W1G   (4 * NF * DEMB) // 2000 floats of w1 per gene
#define MAXG  512             // max genes supported by sort path

#define HTPB   256
#define HCHUNK 4096
#define HFPT   (HCHUNK / HTPB) // 16 fragments per thread in hist/scatter

#define HPAD  11              // fp32 stride of per-wave LDS h tile
#define TKP   208             // transpose tile k-stride (bf16)

typedef __attribute__((ext_vector_type(8))) short short8v;      // 8 bf16
typedef __attribute__((ext_vector_type(4))) unsigned int uint4v;
typedef __attribute__((ext_vector_type(4))) float f32x4v;

__device__ __forceinline__ short f2bf(float f) {
    union { __hip_bfloat16 b; unsigned short u; } v;
    v.b = __float2bfloat16(f);
    return (short)v.u;
}
__device__ __forceinline__ unsigned pkbf(float lo, float hi) {
    union { __hip_bfloat162 b; unsigned u; } v;
    v.b = __float22bfloat162_rn(make_float2(lo, hi));   // .x -> low half
    return v.u;
}

// ---------------------------------------------------------------------------
// K1: hist + out-init + w1 transpose, FUSED with the scan via last-block.
// Scan pads per-gene counts to 256 and emits per-main-block int4 table:
// blk_info[b] = (gene, start_slot, valid_count_in_block, 0);  gene=-1: idle.
// ---------------------------------------------------------------------------
__global__ __launch_bounds__(HTPB) void hist_scan_k(
    const int* __restrict__ gm, const float* __restrict__ w1,
    short* __restrict__ w1T, int n_frag, int n_genes, int nblk,
    int* __restrict__ counts_mat, float* __restrict__ out,
    const float* __restrict__ b2, const int* __restrict__ genes_oi,
    int gene_n, int total, int* __restrict__ done,
    int* __restrict__ cursor, int4* __restrict__ blk_info, int bmax)
{
    __shared__ int lcnt[MAXG];
    __shared__ __align__(16) short tile[DEMB][TKP];
    __shared__ int sbuf[MAXG];
    __shared__ int ticket_s;

    const int tid = threadIdx.x;
    const int bid = blockIdx.x;

    bool do_hist = bid < nblk;
    bool do_tr   = bid < n_genes;

    for (int t = tid; t < MAXG; t += HTPB) lcnt[t] = 0;
    __syncthreads();

    if (do_hist) {
        int base = bid * HCHUNK;
#pragma unroll
        for (int j = 0; j < HFPT; ++j) {
            int f = base + j * HTPB + tid;
            if (f < n_frag) atomicAdd(&lcnt[gm[f]], 1);
        }
    }
    if (do_tr) {
        const float* wg = w1 + (size_t)bid * W1G;
        for (int e4 = tid; e4 < W1G / 4; e4 += HTPB) {
            float4 v = ((const float4*)wg)[e4];
            int e = e4 * 4;
            int k0 = e / 10, d0 = e - k0 * 10;
#pragma unroll
            for (int c = 0; c < 4; ++c) {
                tile[d0][k0] = f2bf((&v.x)[c]);
                d0++; if (d0 == 10) { d0 = 0; k0++; }
            }
        }
    }

    // init out with broadcast b2 (grid-stride)
    int nthreads = gridDim.x * HTPB;
    for (int i = bid * HTPB + tid; i < total; i += nthreads) {
        int col = (int)((unsigned)i % (unsigned)gene_n);
        out[i] = b2[genes_oi[col]];
    }
    // zero tail after last gene's w1T row (kk=6 over-read)
    if (bid == 0 && tid < 64) w1T[(size_t)n_genes * 2000 + tid] = 0;

    __syncthreads();

    if (do_hist) {
        int* row = counts_mat + (size_t)bid * MAXG;
        for (int t = tid; t < MAXG; t += HTPB) row[t] = lcnt[t];
    }
    if (do_tr) {
        short* og = w1T + (size_t)bid * 2000;
        for (int o = tid; o < 250; o += HTPB) {
            int dd = o / 25;
            int off = (o - dd * 25) * 8;
            *(short8v*)(og + dd * 200 + off) = *(const short8v*)&tile[dd][off];
        }
    }

    // ---- last-block scan fusion ----
    __threadfence();
    if (tid == 0) ticket_s = atomicAdd(done, 1);
    __syncthreads();
    if (ticket_s != (int)gridDim.x - 1) return;
    __threadfence();   // acquire: see all blocks' counts_mat rows

    int i0 = tid, i1 = tid + 256;
    int s0 = 0, s1 = 0;
    for (int b = 0; b < nblk; ++b) {
        const int* row = counts_mat + (size_t)b * MAXG;
        s0 += row[i0]; s1 += row[i1];
    }
    int pc0 = ((s0 + 255) >> 8) << 8;       // 256-padded
    int pc1 = ((s1 + 255) >> 8) << 8;
    sbuf[i0] = pc0; sbuf[i1] = pc1;
    __syncthreads();
    for (int ds = 1; ds < MAXG; ds <<= 1) {
        int t0 = (i0 >= ds) ? sbuf[i0 - ds] : 0;
        int t1 = (i1 >= ds) ? sbuf[i1 - ds] : 0;
        __syncthreads();
        sbuf[i0] += t0; sbuf[i1] += t1;
        __syncthreads();
    }
    if (i0 < n_genes) {
        int incl = sbuf[i0];
        int start = incl - pc0;
        cursor[i0] = start;
        int nb = pc0 >> 8;
        for (int j = 0; j < nb; ++j) {
            int lim = s0 - j * 256; lim = (lim < 256) ? lim : 256;
            blk_info[(start >> 8) + j] = make_int4(i0, start + j * 256, lim, 0);
        }
    }
    if (i1 < n_genes) {
        int incl = sbuf[i1];
        int start = incl - pc1;
        cursor[i1] = start;
        int nb = pc1 >> 8;
        for (int j = 0; j < nb; ++j) {
            int lim = s1 - j * 256; lim = (lim < 256) ? lim : 256;
            blk_info[(start >> 8) + j] = make_int4(i1, start + j * 256, lim, 0);
        }
    }
    __syncthreads();
    int Bt = sbuf[n_genes - 1] >> 8;        // total real main blocks
    for (int b = Bt + tid; b < bmax; b += HTPB)
        blk_info[b] = make_int4(-1, 0, 0, 0);
}

// ---------------------------------------------------------------------------
// K2: scatter packed records (coords, bin) into 256-padded gene-sorted order.
// ---------------------------------------------------------------------------
__global__ __launch_bounds__(HTPB) void scatter_k(
    const int* __restrict__ gm, const float* __restrict__ coords,
    const int* __restrict__ lcg, int* __restrict__ cursor,
    float* __restrict__ xs, int* __restrict__ bins,
    int n_frag, int n_genes)
{
    __shared__ int lcnt[MAXG];
    __shared__ int lbase[MAXG];
    for (int t = threadIdx.x; t < MAXG; t += HTPB) lcnt[t] = 0;
    __syncthreads();

    int base = blockIdx.x * HCHUNK;
    int g[HFPT], lr[HFPT];
#pragma unroll
    for (int j = 0; j < HFPT; ++j) {
        int f = base + j * HTPB + (int)threadIdx.x;
        if (f < n_frag) {
            g[j]  = gm[f];
            lr[j] = atomicAdd(&lcnt[g[j]], 1);
        } else {
            g[j] = -1;
        }
    }
    __syncthreads();
    for (int t = threadIdx.x; t < MAXG; t += HTPB) {
        int c = lcnt[t];
        lbase[t] = c ? atomicAdd(&cursor[t], c) : 0;
    }
    __syncthreads();
#pragma unroll
    for (int j = 0; j < HFPT; ++j) {
        if (g[j] >= 0) {
            int f = base + j * HTPB + (int)threadIdx.x;
            int pos = lbase[g[j]] + lr[j];
            float2 xy = ((const float2*)coords)[f];
            xs[2 * pos + 0] = xy.x;
            xs[2 * pos + 1] = xy.y;
            bins[pos] = lcg[f];
        }
    }
}

// ---------------------------------------------------------------------------
// K3: main (MFMA v8) — one block per (gene, 256-frag tile) via int4 blk_info
// (single 16B load resolves gene/start/lim). Gene's 4KB w1T row staged into
// LDS ONCE per block (coalesced) -> B fragments are 7x ds_read_b128, no
// per-lane global B loads on the critical path.
// ---------------------------------------------------------------------------
__global__ __launch_bounds__(256, 4) void main_mfma_k(
    const short* __restrict__ w1T, const float* __restrict__ b1,
    const float* __restrict__ w2, const int* __restrict__ genes_oi,
    const float* __restrict__ xs, const int* __restrict__ bins,
    const int4* __restrict__ blk_info, float* __restrict__ out,
    int gene_n)
{
    __shared__ __align__(16) short Bs[2048];        // gene's w1T row (+pad)
    __shared__ __align__(16) float fr_ext[116];     // fr[i mod 50]
    __shared__ __align__(16) float hb_all[4][64 * HPAD];

    int4 bi = blk_info[blockIdx.x];
    int g = bi.x;
    if (g < 0) return;                              // block-uniform, pre-barrier
    int start = bi.y;
    int lim   = bi.z;

    const int tid = threadIdx.x;

    // ---- stage B row into LDS (250 x 16B) + zero pad [2000,2048) ----
    if (tid < 250) {
        *(short8v*)&Bs[tid * 8] = *(const short8v*)(w1T + (size_t)g * 2000 + tid * 8);
    } else {
        *(short8v*)&Bs[2000 + (tid - 250) * 8] = (short8v)0;
    }
    if (tid < 116) {
        int i = tid;
        int im = (i < 50) ? i : ((i < 100) ? i - 50 : i - 100);
        float ex = (-2.0f * (float)(im + 1) / (float)NF) * 9.965784284662087f; // log2(1000)
        fr_ext[i] = exp2f(ex) * 0.15915494309189535f;   // base/(2*pi): revolutions
    }
    __syncthreads();

    int wid  = tid >> 6;
    int lane = tid & 63;
    if (wid * 64 >= lim) return;                    // wave-uniform, post-barrier

    int d  = lane & 15;                       // output dim / B col
    int q  = lane >> 4;                       // k-group
    int dc = (d < 10) ? d : 9;                // clamped dim (cols 10-15 junk)

    bool valid = (wid * 64 + lane) < lim;
    int pos = start + wid * 64 + lane;

    // ---- round-1 independent global loads ----
    int bin_own = bins[pos];                  // pad slots: garbage, masked later
    float2 xy_m[4];
#pragma unroll
    for (int m = 0; m < 4; ++m)
        xy_m[m] = ((const float2*)xs)[start + wid * 64 + m * 16 + d];
    float b1v = b1[(size_t)g * DEMB + dc];

    // ---- round-2 dependent w2 prefetch ----
    int col_own = (int)((unsigned)bin_own % (unsigned)gene_n);
    int gi = genes_oi[col_own];
    float2 w2v[5];
#pragma unroll
    for (int p2 = 0; p2 < 5; ++p2)
        w2v[p2] = *(const float2*)(w2 + (size_t)gi * DEMB + 2 * p2);

    // ---- B fragments from LDS ----
    const short* bp = Bs + dc * 200 + q * 8;
    short8v breg[7];
#pragma unroll
    for (int kk = 0; kk < 7; ++kk)
        breg[kk] = *(const short8v*)(bp + kk * 32);

    // ---- accumulators init with b1 ----
    f32x4v acc[4];
#pragma unroll
    for (int m = 0; m < 4; ++m) { acc[m][0] = b1v; acc[m][1] = b1v; acc[m][2] = b1v; acc[m][3] = b1v; }

    // ---- MFMA loop: kk outer, m inner ----
#pragma unroll
    for (int kk = 0; kk < 7; ++kk) {
        float4 fv4 = *(const float4*)&fr_ext[16 * kk + 4 * q];
#pragma unroll
        for (int m = 0; m < 4; ++m) {
            uint4v au;
#pragma unroll
            for (int jj = 0; jj < 4; ++jj) {
                int idx = 16 * kk + 4 * q + jj;        // k = 2*idx; idx<50 -> coord0
                float fv = (&fv4.x)[jj];
                float xv = (idx < 50) ? xy_m[m].x : xy_m[m].y;
                float r = xv * fv; r -= rintf(r);      // revolutions in [-0.5,0.5]
                au[jj] = pkbf(__builtin_amdgcn_sinf(r), __builtin_amdgcn_cosf(r));
            }
            if (kk == 6 && q > 0) {                    // k>=200 pad (lane-uniform)
                au[0] = 0; au[1] = 0; au[2] = 0; au[3] = 0;
            }
            short8v afrag = __builtin_bit_cast(short8v, au);
            acc[m] = __builtin_amdgcn_mfma_f32_16x16x32_bf16(afrag, breg[kk], acc[m], 0, 0, 0);
        }
    }

    // ---- epilogue: per-wave LDS h-transpose; lane owns its fragment ----
    float* hb = hb_all[wid];
    if (d < 10) {                              // junk cols must not write (r9 bug)
#pragma unroll
        for (int m = 0; m < 4; ++m)
#pragma unroll
            for (int r = 0; r < 4; ++r)
                hb[(m * 16 + q * 4 + r) * HPAD + d] = acc[m][r];
    }

    float sum = 0.0f;
#pragma unroll
    for (int p2 = 0; p2 < 5; ++p2) {
        float h0 = hb[lane * HPAD + 2 * p2];
        float h1 = hb[lane * HPAD + 2 * p2 + 1];
        sum += w2v[p2].x / (1.0f + __expf(-h0));
        sum += w2v[p2].y / (1.0f + __expf(-h1));
    }
    if (valid) atomicAdd(&out[bin_own], sum);
}

// ---------------------------------------------------------------------------
// Tiny-workspace fallback: one thread per fragment, non-uniform gene
// ---------------------------------------------------------------------------
__global__ __launch_bounds__(256) void frag_naive_k(
    const float* __restrict__ coords, const float* __restrict__ w1,
    const float* __restrict__ b1, const float* __restrict__ w2,
    const int* __restrict__ gm, const int* __restrict__ lcg,
    const int* __restrict__ genes_oi, float* __restrict__ out,
    int gene_n, int n_frag)
{
    __shared__ float fr[NF];
    if (threadIdx.x < NF) {
        float ex = (-2.0f * (float)(threadIdx.x + 1) / (float)NF) * 9.965784284662087f;
        fr[threadIdx.x] = exp2f(ex) * 0.15915494309189535f;
    }
    __syncthreads();

    int f = blockIdx.x * blockDim.x + threadIdx.x;
    if (f >= n_frag) return;
    int g = gm[f];
    const float* wrow  = w1 + (size_t)g * W1G;
    const float* b1row = b1 + (size_t)g * DEMB;
    float x0 = coords[2 * f + 0];
    float x1 = coords[2 * f + 1];

    float h[DEMB];
#pragma unroll
    for (int d = 0; d < DEMB; ++d) h[d] = b1row[d];
#pragma unroll 2
    for (int i = 0; i < NF; ++i) {
        float fv = fr[i];
        float r0 = x0 * fv; r0 -= rintf(r0);
        float r1 = x1 * fv; r1 -= rintf(r1);
        float s0 = __builtin_amdgcn_sinf(r0), c0 = __builtin_amdgcn_cosf(r0);
        float s1 = __builtin_amdgcn_sinf(r1), c1 = __builtin_amdgcn_cosf(r1);
        const float* wa = wrow + (2 * i) * DEMB;
        const float* wb = wrow + (2 * NF + 2 * i) * DEMB;
#pragma unroll
        for (int d = 0; d < DEMB; ++d) {
            h[d] += s0 * wa[d] + c0 * wa[DEMB + d] + s1 * wb[d] + c1 * wb[DEMB + d];
        }
    }
    int bin = lcg[f];
    int col = (int)((unsigned)bin % (unsigned)gene_n);
    const float* w2row = w2 + (size_t)genes_oi[col] * DEMB;
    float sum = 0.0f;
#pragma unroll
    for (int d = 0; d < DEMB; ++d) {
        float sg = 1.0f / (1.0f + __expf(-h[d]));
        sum += sg * w2row[d];
    }
    atomicAdd(&out[bin], sum);
}

__global__ void init_out_k(float* __restrict__ out, const float* __restrict__ b2,
                           const int* __restrict__ genes_oi, int gene_n, int total)
{
    int i = blockIdx.x * blockDim.x + threadIdx.x;
    if (i < total) {
        int col = (int)((unsigned)i % (unsigned)gene_n);
        out[i] = b2[genes_oi[col]];
    }
}

// ---------------------------------------------------------------------------
extern "C" void kernel_launch(void* const* d_in, const int* in_sizes, int n_in,
                              void* d_out, int out_size, void* d_ws, size_t ws_size,
                              hipStream_t stream)
{
    const float* coords   = (const float*)d_in[0];
    const float* w1       = (const float*)d_in[1];
    const float* b1       = (const float*)d_in[2];
    const float* w2       = (const float*)d_in[3];
    const float* b2       = (const float*)d_in[4];
    const int*   gm       = (const int*)d_in[5];
    const int*   lcg      = (const int*)d_in[6];
    const int*   genes_oi = (const int*)d_in[7];

    int n_frag  = in_sizes[5];
    int n_genes = in_sizes[4];
    int gene_n  = in_sizes[7];
    int total   = out_size;
    float* out  = (float*)d_out;

    int nblk = (n_frag + HCHUNK - 1) / HCHUNK;
    int bmax = (n_frag >> 8) + n_genes + 1;            // upper bound on main blocks
    size_t padcap = (size_t)n_frag + 256 * (size_t)n_genes + 256;

    // workspace layout (16B-aligned sections)
    char* p = (char*)d_ws;
    short* w1T = (short*)p;                 p += (((size_t)n_genes * 2000 + 64) * 2 + 15) / 16 * 16;
    int4* blk_info = (int4*)p;              p += (size_t)bmax * 16;
    int* counts_mat = (int*)p;              p += (size_t)nblk * MAXG * 4;
    int* cursor = (int*)p;                  p += MAXG * 4;
    int* done = (int*)p;                    p += 16;
    float* xs = (float*)p;                  p += padcap * 2 * 4;
    int* bins = (int*)p;                    p += padcap * 4;
    size_t need = (size_t)(p - (char*)d_ws);

    bool use_sorted = (ws_size >= need) && (n_genes <= MAXG);
    if (use_sorted) {
        hipMemsetAsync(done, 0, sizeof(int), stream);
        int g1 = (nblk > n_genes) ? nblk : n_genes;
        hist_scan_k<<<g1, HTPB, 0, stream>>>(gm, w1, w1T, n_frag, n_genes, nblk,
                                             counts_mat, out, b2, genes_oi, gene_n,
                                             total, done, cursor, blk_info, bmax);
        scatter_k<<<nblk, HTPB, 0, stream>>>(gm, coords, lcg, cursor,
                                             xs, bins, n_frag, n_genes);
        main_mfma_k<<<bmax, 256, 0, stream>>>(w1T, b1, w2, genes_oi, xs, bins,
                                              blk_info, out, gene_n);
    } else {
        init_out_k<<<(total + 255) / 256, 256, 0, stream>>>(out, b2, genes_oi, gene_n, total);
        frag_naive_k<<<(n_frag + 255) / 256, 256, 0, stream>>>(coords, w1, b1, w2, gm, lcg,
                                                               genes_oi, out, gene_n, n_frag);
    }
}